// Round 9
// baseline (55.953 us; speedup 1.0000x reference)
//
#include <hip/hip_runtime.h>
#include <hip/hip_bf16.h>
#include <math.h>

// Reference collapses (softmax over size-1 axis == 1) to:
//   s[b,n] = sum_k x[b,k] * W'[k,n]   (M=256, N=160, K=9216)
//   W'[p*8+j][d*16+i] = W[p][d][i][j]; then squash over 16-groups of n.
// bf16 MFMA path (threshold 1.5e-2 >> bf16 error ~4e-3).
// Single kernel, stream-k style: split-K partials + per-mtile ticket counter;
// ticket 28..31 blocks spin (all blocks resident at grid=256), acquire-fence,
// reduce one 8-row quarter + squash. No second dispatch, no grid.sync.
#define M 256
#define N 160
#define K 9216
#define CH 32     // k-chunks
#define KC 288    // k per chunk = 36 p (3 stages of 12 p)
#define BM 32
#define XST 104   // Xl row stride (shorts)

#define PART_F32 ((size_t)CH * M * N)  // 1310720 floats = 5.24 MB

using f32x4 = __attribute__((ext_vector_type(4))) float;
using bf16x8 = __attribute__((ext_vector_type(8))) short;

__device__ __forceinline__ ushort f2bf(float f) {
  return __builtin_bit_cast(ushort, __float2bfloat16(f));
}

// grid = 8 m-tiles * 32 chunks = 256 blocks, 256 thr (4 waves).
__global__ __launch_bounds__(256) void fused_gemm(const float* __restrict__ x,
                                                  const float* __restrict__ W,
                                                  float* __restrict__ part,
                                                  int* __restrict__ cnt,
                                                  float* __restrict__ out) {
  __shared__ ushort Wl[12 * 1280];            // 12 p, bf16, source order
  __shared__ __align__(16) ushort Xl[BM * XST];
  __shared__ int s_old;

  const int t = threadIdx.x;
  const int bx = blockIdx.x;
  const int mt = bx & 7;
  const int c = bx >> 3;  // 0..31
  const int m0 = mt * BM;
  const int k0 = c * KC;

  const int w = t >> 6;
  const int l = t & 63;
  const int lr = l & 15;
  const int lg = l >> 4;
  const int msub = w & 1;
  const int nh = w >> 1;

  float4 wv[15], xv[3];
  int xrow[3], xkq[3];
#pragma unroll
  for (int q = 0; q < 3; ++q) {
    const int f = t + 256 * q;
    xrow[q] = f / 24;
    xkq[q] = (f - xrow[q] * 24) * 4;
  }

  auto load = [&](int s) {
    const float* wsp = W + ((size_t)c * 36 + s * 12) * 1280;
#pragma unroll
    for (int q = 0; q < 15; ++q)
      wv[q] = *(const float4*)(wsp + 4 * (size_t)(t + 256 * q));
    const float* xs = x + (size_t)m0 * K + k0 + s * 96;
#pragma unroll
    for (int q = 0; q < 3; ++q)
      xv[q] = *(const float4*)(xs + (size_t)xrow[q] * K + xkq[q]);
  };
  auto put = [&]() {
#pragma unroll
    for (int q = 0; q < 15; ++q) {
      const int f4 = t + 256 * q;
      ushort4 h = {f2bf(wv[q].x), f2bf(wv[q].y), f2bf(wv[q].z), f2bf(wv[q].w)};
      *(ushort4*)&Wl[4 * f4] = h;
    }
#pragma unroll
    for (int q = 0; q < 3; ++q) {
      ushort4 h = {f2bf(xv[q].x), f2bf(xv[q].y), f2bf(xv[q].z), f2bf(xv[q].w)};
      *(ushort4*)&Xl[xrow[q] * XST + xkq[q]] = h;
    }
  };

  f32x4 acc[5];
#pragma unroll
  for (int nt = 0; nt < 5; ++nt) acc[nt] = {0.f, 0.f, 0.f, 0.f};

  auto comp = [&]() {
#pragma unroll
    for (int ks = 0; ks < 3; ++ks) {
      const bf16x8 a =
          *(const bf16x8*)&Xl[(msub * 16 + lr) * XST + ks * 32 + lg * 8];
#pragma unroll
      for (int nt = 0; nt < 5; ++nt) {
        const bf16x8 b =
            *(const bf16x8*)&Wl[(ks * 4 + lg) * 1280 + (nh * 5 + nt) * 128 +
                                lr * 8];
        acc[nt] =
            __builtin_amdgcn_mfma_f32_16x16x32_bf16(a, b, acc[nt], 0, 0, 0);
      }
    }
  };

  load(0);
  put();
  __syncthreads();
  load(1);
  comp();
  __syncthreads();
  put();
  __syncthreads();
  load(2);
  comp();
  __syncthreads();
  put();
  __syncthreads();
  comp();

  // store partials: C row = (lane>>4)*4 + reg, col = lane&15 (verified)
  {
    float* dst = part + (size_t)c * (M * N);
#pragma unroll
    for (int nt = 0; nt < 5; ++nt)
#pragma unroll
      for (int r = 0; r < 4; ++r) {
        const int row = m0 + msub * 16 + lg * 4 + r;
        dst[(size_t)row * N + (nh * 5 + nt) * 16 + lr] = acc[nt][r];
      }
  }

  // ---- publish: release own stores, take a ticket ----
  __threadfence();   // device-scope release of this thread's partial stores
  __syncthreads();
  if (t == 0)
    s_old = __hip_atomic_fetch_add(&cnt[mt], 1, __ATOMIC_ACQ_REL,
                                   __HIP_MEMORY_SCOPE_AGENT);
  __syncthreads();
  const int old = s_old;
  if (old < CH - 4) return;   // tickets 0..27: done
  const int q = old - (CH - 4);  // quarter 0..3 (rows m0+q*8 .. +8)

  // ---- wait for all 32 chunks of this m-tile (blocks already resident) ----
  if (t == 0) {
    while (__hip_atomic_load(&cnt[mt], __ATOMIC_ACQUIRE,
                             __HIP_MEMORY_SCOPE_AGENT) < CH) {
    }
  }
  __syncthreads();
  __threadfence();   // acquire: invalidate local caches -> fresh partials

  // ---- phase A: reduce 8 rows x 160 cols over 32 chunks -> LDS ----
  f32x4* sm = (f32x4*)Xl;              // 320 f32x4 = 5.1 KB (Xl is 6.5 KB)
  const f32x4* p4 = (const f32x4*)part;
  const int rbase = m0 + q * 8;
  {
    const int v = t;                   // vec 0..255
    const int row_l = v / 40;
    const int n4 = v - row_l * 40;
    const int vi = (rbase + row_l) * 40 + n4;
    f32x4 s = {0.f, 0.f, 0.f, 0.f};
#pragma unroll 8
    for (int cc = 0; cc < CH; ++cc) s += p4[(size_t)cc * (M * N / 4) + vi];
    sm[v] = s;
  }
  if (t < 64) {
    const int v = 256 + t;             // vec 256..319
    const int row_l = v / 40;
    const int n4 = v - row_l * 40;
    const int vi = (rbase + row_l) * 40 + n4;
    f32x4 s = {0.f, 0.f, 0.f, 0.f};
#pragma unroll 8
    for (int cc = 0; cc < CH; ++cc) s += p4[(size_t)cc * (M * N / 4) + vi];
    sm[v] = s;
  }
  __syncthreads();

  // ---- phase B: squash 80 d-groups (8 rows x 10 d), write out ----
  if (t < 80) {
    const int row_l = t / 10;
    const int cb4 = (t - row_l * 10) * 4;      // f32x4 base within row
    const f32x4 a = sm[row_l * 40 + cb4 + 0];
    const f32x4 b = sm[row_l * 40 + cb4 + 1];
    const f32x4 cq = sm[row_l * 40 + cb4 + 2];
    const f32x4 d = sm[row_l * 40 + cb4 + 3];
    float n2 = a[0] * a[0] + a[1] * a[1] + a[2] * a[2] + a[3] * a[3] +
               b[0] * b[0] + b[1] * b[1] + b[2] * b[2] + b[3] * b[3] +
               cq[0] * cq[0] + cq[1] * cq[1] + cq[2] * cq[2] + cq[3] * cq[3] +
               d[0] * d[0] + d[1] * d[1] + d[2] * d[2] + d[3] * d[3];
    const float sc = n2 / (1.0f + n2) / sqrtf(n2 + 1e-9f);
    f32x4* o4 = (f32x4*)out;
    const int ob = (rbase + row_l) * 40 + cb4;
    o4[ob + 0] = a * sc;
    o4[ob + 1] = b * sc;
    o4[ob + 2] = cq * sc;
    o4[ob + 3] = d * sc;
  }
}

// ---------- fallback (ws too small): atomic gemm + squash ----------
__global__ __launch_bounds__(256) void gemm_atomic(const float* __restrict__ x,
                                                   const float* __restrict__ W,
                                                   float* __restrict__ outp) {
  __shared__ ushort Wl[12 * 1280];
  __shared__ ushort Xl[BM * XST];
  const int t = threadIdx.x;
  const int bx = blockIdx.x;
  const int mt = bx & 7;
  const int c = bx >> 3;
  const int m0 = mt * BM;
  const int k0 = c * KC;
  const int w = t >> 6;
  const int l = t & 63;
  const int lr = l & 15;
  const int lg = l >> 4;
  const int msub = w & 1;
  const int nh = w >> 1;
  float4 wv[15], xv[3];
  int xrow[3], xkq[3];
#pragma unroll
  for (int q = 0; q < 3; ++q) {
    const int f = t + 256 * q;
    xrow[q] = f / 24;
    xkq[q] = (f - xrow[q] * 24) * 4;
  }
  auto load = [&](int s) {
    const float* wsp = W + ((size_t)c * 36 + s * 12) * 1280;
#pragma unroll
    for (int q = 0; q < 15; ++q)
      wv[q] = *(const float4*)(wsp + 4 * (size_t)(t + 256 * q));
    const float* xs = x + (size_t)m0 * K + k0 + s * 96;
#pragma unroll
    for (int q = 0; q < 3; ++q)
      xv[q] = *(const float4*)(xs + (size_t)xrow[q] * K + xkq[q]);
  };
  auto put = [&]() {
#pragma unroll
    for (int q = 0; q < 15; ++q) {
      const int f4 = t + 256 * q;
      ushort4 h = {f2bf(wv[q].x), f2bf(wv[q].y), f2bf(wv[q].z), f2bf(wv[q].w)};
      *(ushort4*)&Wl[4 * f4] = h;
    }
#pragma unroll
    for (int q = 0; q < 3; ++q) {
      ushort4 h = {f2bf(xv[q].x), f2bf(xv[q].y), f2bf(xv[q].z), f2bf(xv[q].w)};
      *(ushort4*)&Xl[xrow[q] * XST + xkq[q]] = h;
    }
  };
  f32x4 acc[5];
#pragma unroll
  for (int nt = 0; nt < 5; ++nt) acc[nt] = {0.f, 0.f, 0.f, 0.f};
  auto comp = [&]() {
#pragma unroll
    for (int ks = 0; ks < 3; ++ks) {
      const bf16x8 a =
          *(const bf16x8*)&Xl[(msub * 16 + lr) * XST + ks * 32 + lg * 8];
#pragma unroll
      for (int nt = 0; nt < 5; ++nt) {
        const bf16x8 b =
            *(const bf16x8*)&Wl[(ks * 4 + lg) * 1280 + (nh * 5 + nt) * 128 +
                                lr * 8];
        acc[nt] =
            __builtin_amdgcn_mfma_f32_16x16x32_bf16(a, b, acc[nt], 0, 0, 0);
      }
    }
  };
  load(0);
  put();
  __syncthreads();
  load(1);
  comp();
  __syncthreads();
  put();
  __syncthreads();
  load(2);
  comp();
  __syncthreads();
  put();
  __syncthreads();
  comp();
#pragma unroll
  for (int nt = 0; nt < 5; ++nt)
#pragma unroll
    for (int r = 0; r < 4; ++r) {
      const int row = m0 + msub * 16 + lg * 4 + r;
      atomicAdd(&outp[(size_t)row * N + (nh * 5 + nt) * 16 + lr], acc[nt][r]);
    }
}

__global__ __launch_bounds__(256) void squash_k(float* __restrict__ out) {
  const int e = blockIdx.x * 256 + threadIdx.x;
  const float s = out[e];
  float s2 = s * s;
  s2 += __shfl_xor(s2, 1);
  s2 += __shfl_xor(s2, 2);
  s2 += __shfl_xor(s2, 4);
  s2 += __shfl_xor(s2, 8);
  out[e] = s * s2 / (1.0f + s2) / sqrtf(s2 + 1e-9f);
}

extern "C" void kernel_launch(void* const* d_in, const int* in_sizes, int n_in,
                              void* d_out, int out_size, void* d_ws,
                              size_t ws_size, hipStream_t stream) {
  const float* x = (const float*)d_in[0];  // [256,1152,8,1]
  const float* W = (const float*)d_in[1];  // [1152,10,16,8]
  float* out = (float*)d_out;              // [256,10,16,1] = 40960 f32

  const size_t need = PART_F32 * sizeof(float) + 64;  // partials + counters
  if (ws_size >= need) {
    float* part = (float*)d_ws;
    int* cnt = (int*)((char*)d_ws + PART_F32 * sizeof(float));
    hipMemsetAsync(cnt, 0, 8 * sizeof(int), stream);  // tickets = 0 each call
    fused_gemm<<<256, 256, 0, stream>>>(x, W, part, cnt, out);
  } else {
    hipMemsetAsync(out, 0, (size_t)M * N * sizeof(float), stream);
    gemm_atomic<<<256, 256, 0, stream>>>(x, W, out);
    squash_k<<<(M * N) / 256, 256, 0, stream>>>(out);
  }
}

// Round 10
// 20.729 us; speedup vs baseline: 2.6993x; 2.6993x over previous
//
#include <hip/hip_runtime.h>
#include <hip/hip_bf16.h>
#include <math.h>

// Reference collapses (softmax over size-1 axis == 1) to:
//   s[b,n] = sum_k x[b,k] * W'[k,n]   (M=256, N=160, K=9216)
//   W'[p*8+j][d*16+i] = W[p][d][i][j]; then squash over 16-groups of n.
// bf16 MFMA path (threshold 1.5e-2 >> bf16 error ~4e-3).
#define M 256
#define N 160
#define K 9216
#define CH 72     // k-chunks
#define KC 128    // k per chunk = 16 p (4 sub-stages of 4 p)
#define BM 32
#define WPS 1296  // Wl per-p stride (shorts): 1280 + 16 pad (bank spread)
#define XSTR 136  // Xl row stride (shorts): 128 + 8 pad

using f32x4 = __attribute__((ext_vector_type(4))) float;
using bf16x8 = __attribute__((ext_vector_type(8))) short;

__device__ __forceinline__ ushort f2bf(float f) {
  return __builtin_bit_cast(ushort, __float2bfloat16(f));
}

// grid = 8 m-tiles * 72 chunks = 576 blocks, 256 thr (4 waves).
// ~29 KB LDS -> 3+ blocks/CU resident (the R7 killer was 1 block/CU).
// Wave w: rows m0+(w&1)*16, n-tiles (w>>1)*5..+4; 20 MFMA/wave.
template <bool ATOMIC>
__global__ __launch_bounds__(256) void gemm_mfma(const float* __restrict__ x,
                                                 const float* __restrict__ W,
                                                 float* __restrict__ part) {
  __shared__ __align__(16) ushort Wl[2][4 * WPS];  // 2 bufs x 4 p
  __shared__ __align__(16) ushort Xl[BM * XSTR];   // full 128-k X tile

  const int t = threadIdx.x;
  const int bx = blockIdx.x;
  const int mt = bx & 7;
  const int c = bx >> 3;  // 0..71
  const int m0 = mt * BM;
  const int k0 = c * KC;

  const int w = t >> 6;
  const int l = t & 63;
  const int lr = l & 15;
  const int lg = l >> 4;
  const int msub = w & 1;
  const int nh = w >> 1;  // n-tile base = nh*5

  // ---- stage X tile once: 32 rows x 128 k, 4 f4/thread ----
  {
    const float* xs = x + (size_t)m0 * K + k0;
#pragma unroll
    for (int q = 0; q < 4; ++q) {
      const int f = t + 256 * q;    // f4 idx < 1024
      const int row = f >> 5;
      const int kq4 = f & 31;
      const float4 v = *(const float4*)(xs + (size_t)row * K + kq4 * 4);
      ushort4 h = {f2bf(v.x), f2bf(v.y), f2bf(v.z), f2bf(v.w)};
      *(ushort4*)&Xl[row * XSTR + kq4 * 4] = h;
    }
  }

  // ---- W sub-stage machinery: 4 p per stage, 5 f4/thread ----
  float4 wv[5];
  auto loadW = [&](int s) {
    const float* wsp = W + ((size_t)c * 16 + s * 4) * 1280;
#pragma unroll
    for (int q = 0; q < 5; ++q)
      wv[q] = *(const float4*)(wsp + 4 * (size_t)(t + 256 * q));
  };
  auto putW = [&](int b) {
#pragma unroll
    for (int q = 0; q < 5; ++q) {
      const int e = t + 256 * q;    // f4 idx < 1280
      const int pl = e / 320;       // p-local 0..3
      const int r4 = e - pl * 320;
      ushort4 h = {f2bf(wv[q].x), f2bf(wv[q].y), f2bf(wv[q].z), f2bf(wv[q].w)};
      *(ushort4*)&Wl[b][pl * WPS + r4 * 4] = h;
    }
  };

  f32x4 acc[5];
#pragma unroll
  for (int nt = 0; nt < 5; ++nt) acc[nt] = {0.f, 0.f, 0.f, 0.f};

  auto comp = [&](int b, int s) {
    const bf16x8 a =
        *(const bf16x8*)&Xl[(msub * 16 + lr) * XSTR + s * 32 + lg * 8];
#pragma unroll
    for (int nt = 0; nt < 5; ++nt) {
      // B[k=lg*8+j][n=(nh*5+nt)*16+lr] = W[p0+s*4+lg][d][i=lr][j]
      const bf16x8 bb =
          *(const bf16x8*)&Wl[b][lg * WPS + (nh * 5 + nt) * 128 + lr * 8];
      acc[nt] = __builtin_amdgcn_mfma_f32_16x16x32_bf16(a, bb, acc[nt], 0, 0, 0);
    }
  };

  // ---- 4-stage double-buffered pipeline, 1-ahead reg prefetch ----
  loadW(0);
  putW(0);
  __syncthreads();
  loadW(1);
  comp(0, 0);
  putW(1);
  __syncthreads();
  loadW(2);
  comp(1, 1);
  putW(0);
  __syncthreads();
  loadW(3);
  comp(0, 2);
  putW(1);
  __syncthreads();
  comp(1, 3);

  // ---- store: C row = (lane>>4)*4 + reg, col = lane&15 (verified) ----
  if (ATOMIC) {
#pragma unroll
    for (int nt = 0; nt < 5; ++nt)
#pragma unroll
      for (int r = 0; r < 4; ++r) {
        const int row = m0 + msub * 16 + lg * 4 + r;
        atomicAdd(&part[(size_t)row * N + (nh * 5 + nt) * 16 + lr],
                  acc[nt][r]);
      }
  } else {
    float* dst = part + (size_t)c * (M * N);
#pragma unroll
    for (int nt = 0; nt < 5; ++nt)
#pragma unroll
      for (int r = 0; r < 4; ++r) {
        const int row = m0 + msub * 16 + lg * 4 + r;
        dst[(size_t)row * N + (nh * 5 + nt) * 16 + lr] = acc[nt][r];
      }
  }
}

// Vectorized reduce (72 chunks) + squash. grid = 160 blocks, 256 thr.
__global__ __launch_bounds__(256) void reduce_squash4(
    const float* __restrict__ part, float* __restrict__ out) {
  __shared__ f32x4 red[256];
  const int t = threadIdx.x;
  const int o4 = t & 63;
  const int slice = t >> 6;  // 0..3, 18 chunks each
  const f32x4* p4 = (const f32x4*)part;
  const int base4 = blockIdx.x * 64;

  f32x4 sum = {0.f, 0.f, 0.f, 0.f};
#pragma unroll 6
  for (int cc = 0; cc < 18; ++cc) {
    const int c = slice * 18 + cc;
    sum += p4[(size_t)c * (M * N / 4) + base4 + o4];
  }
  red[t] = sum;
  __syncthreads();
  if (t < 64) {
    const f32x4 s = red[t] + red[t + 64] + red[t + 128] + red[t + 192];
    float n2 = s[0] * s[0] + s[1] * s[1] + s[2] * s[2] + s[3] * s[3];
    n2 += __shfl_xor(n2, 1);  // quad = one 16-elem group
    n2 += __shfl_xor(n2, 2);
    const float sc = n2 / (1.0f + n2) / sqrtf(n2 + 1e-9f);
    f32x4 o = {s[0] * sc, s[1] * sc, s[2] * sc, s[3] * sc};
    ((f32x4*)out)[base4 + t] = o;
  }
}

__global__ __launch_bounds__(256) void squash_k(float* __restrict__ out) {
  const int e = blockIdx.x * 256 + threadIdx.x;
  const float s = out[e];
  float s2 = s * s;
  s2 += __shfl_xor(s2, 1);
  s2 += __shfl_xor(s2, 2);
  s2 += __shfl_xor(s2, 4);
  s2 += __shfl_xor(s2, 8);
  out[e] = s * s2 / (1.0f + s2) / sqrtf(s2 + 1e-9f);
}

extern "C" void kernel_launch(void* const* d_in, const int* in_sizes, int n_in,
                              void* d_out, int out_size, void* d_ws,
                              size_t ws_size, hipStream_t stream) {
  const float* x = (const float*)d_in[0];  // [256,1152,8,1]
  const float* W = (const float*)d_in[1];  // [1152,10,16,8]
  float* out = (float*)d_out;              // [256,10,16,1] = 40960 f32

  const size_t need = (size_t)CH * M * N * sizeof(float);  // 11.8 MB
  if (ws_size >= need) {
    gemm_mfma<false><<<8 * CH, 256, 0, stream>>>(x, W, (float*)d_ws);
    reduce_squash4<<<(M * N) / 256, 256, 0, stream>>>((const float*)d_ws, out);
  } else {
    hipMemsetAsync(out, 0, (size_t)M * N * sizeof(float), stream);
    gemm_mfma<true><<<8 * CH, 256, 0, stream>>>(x, W, out);
    squash_k<<<(M * N) / 256, 256, 0, stream>>>(out);
  }
}